// Round 4
// baseline (144.395 us; speedup 1.0000x reference)
//
#include <hip/hip_runtime.h>
#include <stdint.h>

#define B_ 4
#define S_ 2048
#define D_ 768
#define U_ 768

typedef __bf16 bf16x8 __attribute__((ext_vector_type(8)));
typedef float f32x4 __attribute__((ext_vector_type(4)));

#define AS1 __attribute__((address_space(1)))
#define AS3 __attribute__((address_space(3)))

#define BAR() __builtin_amdgcn_s_barrier()
#define WAITV6() asm volatile("s_waitcnt vmcnt(6)" ::: "memory")
#define WAITV4() asm volatile("s_waitcnt vmcnt(4)" ::: "memory")
#define WAITV0() asm volatile("s_waitcnt vmcnt(0)" ::: "memory")
#define PRIO(x) __builtin_amdgcn_s_setprio(x)

__device__ __forceinline__ ushort f2bf(float f) {
    union { float f; uint32_t u; } v; v.f = f;
    uint32_t r = v.u + 0x7fffu + ((v.u >> 16) & 1u);
    return (ushort)(r >> 16);
}

__device__ __forceinline__ void gload_lds16(const void* gp, void* lp) {
    // width-16 global->LDS: HW scatters to (wave-uniform lds base) + lane*16
    __builtin_amdgcn_global_load_lds((AS1 void*)gp, (AS3 void*)lp, 16, 0, 0);
}

// ============================================================================
// 256x256 8-phase pipelined GEMM (proven r2 path — used by scores only).
// ============================================================================
template <int MODE>  // 2: f32*scale
__device__ __forceinline__ void gemm256(
    ushort* sm,
    const ushort* __restrict__ Ag, int lda,
    const ushort* __restrict__ Btg, int ldb,
    void* __restrict__ Cp, int ldc, int Kd, float scale,
    int ty, int tx)
{
    constexpr int ABUF = 256 * 64;
    ushort* sA = sm;
    ushort* sB = sm + 2 * ABUF;

    const int tid = threadIdx.x;
    const int l = tid & 63, w = tid >> 6;
    const int lr = l & 15, lg = l >> 4;
    const int wm = w >> 2, wn = w & 3;
    const int M0 = ty * 256, N0 = tx * 256;

    f32x4 acc[8][4];
#pragma unroll
    for (int m = 0; m < 8; ++m)
#pragma unroll
        for (int n = 0; n < 4; ++n)
            acc[m][n] = (f32x4){0.f, 0.f, 0.f, 0.f};

    const int NT = Kd >> 6;

    auto STA = [&](int buf, int qp, int kt) {
#pragma unroll
        for (int j = 0; j < 2; ++j) {
            int q = qp + j;
            int r0 = (w < 4) ? (q * 32 + w * 8) : (128 + q * 32 + (w - 4) * 8);
            int r = r0 + (l >> 3);
            int lc = ((l & 7) * 16) ^ ((r & 7) << 4);
            gload_lds16(Ag + (size_t)(M0 + r) * lda + kt * 64 + (lc >> 1),
                        sA + buf * ABUF + r0 * 64);
        }
    };
    auto STB = [&](int buf, int h, int kt) {
#pragma unroll
        for (int j = 0; j < 2; ++j) {
            int r0 = h * 128 + j * 64 + w * 8;
            int r = r0 + (l >> 3);
            int lc = ((l & 7) * 16) ^ ((r & 7) << 4);
            gload_lds16(Btg + (size_t)(N0 + r) * ldb + kt * 64 + (lc >> 1),
                        sB + buf * 16384 + r0 * 64);
        }
    };

    bf16x8 afr[2][2], bfr[4][2];
    auto LDB = [&](int buf) {
#pragma unroll
        for (int nf = 0; nf < 4; ++nf)
#pragma unroll
            for (int ks = 0; ks < 2; ++ks) {
                int r = wn * 64 + nf * 16 + lr;
                int off = r * 128 + ((ks * 64 + lg * 16) ^ ((r & 7) << 4));
                bfr[nf][ks] = *(const bf16x8*)((const char*)(sB + buf * 16384) + off);
            }
    };
    auto LDA = [&](int buf, int q) {
#pragma unroll
        for (int j = 0; j < 2; ++j)
#pragma unroll
            for (int ks = 0; ks < 2; ++ks) {
                int r = wm * 128 + (2 * q + j) * 16 + lr;
                int off = r * 128 + ((ks * 64 + lg * 16) ^ ((r & 7) << 4));
                afr[j][ks] = *(const bf16x8*)((const char*)(sA + buf * ABUF) + off);
            }
    };

#define MMQ(Q)                                                                 \
    PRIO(1);                                                                   \
    _Pragma("unroll")                                                          \
    for (int j = 0; j < 2; ++j)                                                \
        _Pragma("unroll")                                                      \
        for (int nf = 0; nf < 4; ++nf)                                         \
            _Pragma("unroll")                                                  \
            for (int ks = 0; ks < 2; ++ks)                                     \
                acc[2 * (Q) + j][nf] = __builtin_amdgcn_mfma_f32_16x16x32_bf16(\
                    afr[j][ks], bfr[nf][ks], acc[2 * (Q) + j][nf], 0, 0, 0);   \
    PRIO(0);

    STA(0, 0, 0); STA(0, 2, 0); STB(0, 0, 0); STB(0, 1, 0);
    if (NT > 1) {
        STB(1, 0, 1); STB(1, 1, 1); STA(1, 0, 1);
        WAITV6();
    } else {
        WAITV0();
    }
    BAR();

    for (int t = 0; t < NT; ++t) {
        const int c = t & 1;
        LDB(c); LDA(c, 0);
        if (t + 1 < NT) STA(c ^ 1, 2, t + 1);
        BAR();
        MMQ(0);
        BAR();
        LDA(c, 1);
        if (t + 2 < NT) STB(c, 0, t + 2);
        BAR();
        MMQ(1);
        BAR();
        LDA(c, 2);
        if (t + 2 < NT) STB(c, 1, t + 2);
        BAR();
        MMQ(2);
        BAR();
        LDA(c, 3);
        if (t + 2 < NT) STA(c, 0, t + 2);
        BAR();
        MMQ(3);
        if (t + 2 < NT) { WAITV6(); } else { WAITV0(); }
        BAR();
    }
#undef MMQ

#pragma unroll
    for (int mf = 0; mf < 8; ++mf)
#pragma unroll
        for (int nf = 0; nf < 4; ++nf)
#pragma unroll
            for (int i = 0; i < 4; ++i) {
                int r = M0 + wm * 128 + mf * 16 + lg * 4 + i;
                int c = N0 + wn * 64 + nf * 16 + lr;
                ((float*)Cp)[(size_t)r * ldc + c] = acc[mf][nf][i] * scale;
            }
}

// ============================================================================
// 128x256 2-compute-phase pipelined GEMM (BK=64, 8 waves 2Mx4N, per-wave
// 64x64, 16 MFMA per phase, 4 barriers/K-tile, counted vmcnt(4)).
// Per K-tile t (c = t&1):
//   p0: LDB(c) 8ds + LDA half0 4ds; stage A(t+1)->c^1 (2 gl); BAR; 16 MFMA; BAR
//   p1: LDA half1 4ds; stage B0,B1(t+2)->c (4 gl); BAR; 16 MFMA; vmcnt(4); BAR
// WAR discipline: every LDS region has >=2 barriers + lgkm-guarded consume
// between read-issue and conflicting DMA-write-issue (same as 8-phase).
// LDS: sA[2][128*64] + sB[2][256*64] bf16 = 96 KiB.
// ============================================================================
template <int MODE>  // 0: bf16 out, 1: bf16 -> [B][U][S], 2: f32*scale
__device__ __forceinline__ void gemm128_2ph(
    ushort* sm,
    const ushort* __restrict__ Ag, int lda,
    const ushort* __restrict__ Btg, int ldb,
    void* __restrict__ Cp, int ldc, int Kd, float scale,
    int ty, int tx)
{
    constexpr int ABUF = 128 * 64;
    ushort* sA = sm;
    ushort* sB = sm + 2 * ABUF;

    const int tid = threadIdx.x;
    const int l = tid & 63, w = tid >> 6;
    const int lr = l & 15, lg = l >> 4;
    const int wm = w >> 2, wn = w & 3;
    const int M0 = ty * 128, N0 = tx * 256;

    f32x4 acc[4][4];
#pragma unroll
    for (int m = 0; m < 4; ++m)
#pragma unroll
        for (int n = 0; n < 4; ++n)
            acc[m][n] = (f32x4){0.f, 0.f, 0.f, 0.f};

    const int NT = Kd >> 6;

    // stage full A tile (128x64) of K-tile kt: 2 gloads/thread
    auto STA = [&](int buf, int kt) {
#pragma unroll
        for (int j = 0; j < 2; ++j) {
            int r0 = w * 16 + j * 8;
            int r = r0 + (l >> 3);
            int lc = ((l & 7) * 16) ^ ((r & 7) << 4);
            gload_lds16(Ag + (size_t)(M0 + r) * lda + kt * 64 + (lc >> 1),
                        sA + buf * ABUF + r0 * 64);
        }
    };
    auto STB = [&](int buf, int h, int kt) {
#pragma unroll
        for (int j = 0; j < 2; ++j) {
            int r0 = h * 128 + j * 64 + w * 8;
            int r = r0 + (l >> 3);
            int lc = ((l & 7) * 16) ^ ((r & 7) << 4);
            gload_lds16(Btg + (size_t)(N0 + r) * ldb + kt * 64 + (lc >> 1),
                        sB + buf * 16384 + r0 * 64);
        }
    };

    bf16x8 afr[2][2], bfr[4][2];
    auto LDB = [&](int buf) {
#pragma unroll
        for (int nf = 0; nf < 4; ++nf)
#pragma unroll
            for (int ks = 0; ks < 2; ++ks) {
                int r = wn * 64 + nf * 16 + lr;
                int off = r * 128 + ((ks * 64 + lg * 16) ^ ((r & 7) << 4));
                bfr[nf][ks] = *(const bf16x8*)((const char*)(sB + buf * 16384) + off);
            }
    };
    // load A frag pair h (mf = 2h, 2h+1)
    auto LDA2 = [&](int buf, int h) {
#pragma unroll
        for (int j = 0; j < 2; ++j)
#pragma unroll
            for (int ks = 0; ks < 2; ++ks) {
                int r = wm * 64 + (2 * h + j) * 16 + lr;
                int off = r * 128 + ((ks * 64 + lg * 16) ^ ((r & 7) << 4));
                afr[j][ks] = *(const bf16x8*)((const char*)(sA + buf * ABUF) + off);
            }
    };

#define MMH(H)                                                                 \
    PRIO(1);                                                                   \
    _Pragma("unroll")                                                          \
    for (int j = 0; j < 2; ++j)                                                \
        _Pragma("unroll")                                                      \
        for (int nf = 0; nf < 4; ++nf)                                         \
            _Pragma("unroll")                                                  \
            for (int ks = 0; ks < 2; ++ks)                                     \
                acc[2 * (H) + j][nf] = __builtin_amdgcn_mfma_f32_16x16x32_bf16(\
                    afr[j][ks], bfr[nf][ks], acc[2 * (H) + j][nf], 0, 0, 0);   \
    PRIO(0);

    // prologue: tile0 fully (6 loads) + tile1's B (4 loads)
    STA(0, 0); STB(0, 0, 0); STB(0, 1, 0);
    if (NT > 1) {
        STB(1, 0, 1); STB(1, 1, 1);
        WAITV4();
    } else {
        WAITV0();
    }
    BAR();

    for (int t = 0; t < NT; ++t) {
        const int c = t & 1;
        // phase 0
        LDB(c); LDA2(c, 0);
        if (t + 1 < NT) STA(c ^ 1, t + 1);
        BAR();
        MMH(0);
        BAR();
        // phase 1
        LDA2(c, 1);
        if (t + 2 < NT) { STB(c, 0, t + 2); STB(c, 1, t + 2); }
        BAR();
        MMH(1);
        if (t + 2 < NT) { WAITV4(); } else { WAITV0(); }
        BAR();
    }
#undef MMH

    // epilogue: C/D frag mapping col = lane&15, row = (lane>>4)*4 + i
#pragma unroll
    for (int mf = 0; mf < 4; ++mf) {
#pragma unroll
        for (int nf = 0; nf < 4; ++nf) {
#pragma unroll
            for (int i = 0; i < 4; ++i) {
                int r = M0 + wm * 64 + mf * 16 + lg * 4 + i;
                int c = N0 + wn * 64 + nf * 16 + lr;
                float v = acc[mf][nf][i];
                if constexpr (MODE == 0) {
                    ((ushort*)Cp)[(size_t)r * ldc + c] = f2bf(v);
                } else if constexpr (MODE == 1) {
                    int b = r >> 11, s = r & 2047;  // rows are b*S + s
                    ((ushort*)Cp)[((size_t)b * U_ + c) * S_ + s] = f2bf(v);
                } else {
                    ((float*)Cp)[(size_t)r * ldc + c] = v * scale;
                }
            }
        }
    }
}

__global__ __launch_bounds__(512) void proj_kernel(
    const ushort* __restrict__ xb, const ushort* __restrict__ Wt,
    ushort* __restrict__ Qb, ushort* __restrict__ Kb, ushort* __restrict__ Vt) {
    extern __shared__ ushort sm[];
    const int nwg = 576;                             // 64 ty x 3 tx x 3 z
    const int b0 = blockIdx.x;
    const int wg = (b0 & 7) * (nwg >> 3) + (b0 >> 3);  // XCD-contiguous
    const int z = wg / 192, rem = wg % 192;
    const int ty = rem / 3, tx = rem % 3;
    const ushort* Btz = Wt + (size_t)z * U_ * D_;
    if (z == 0)
        gemm128_2ph<0>(sm, xb, D_, Btz, D_, Qb, U_, D_, 1.f, ty, tx);
    else if (z == 1)
        gemm128_2ph<0>(sm, xb, D_, Btz, D_, Kb, U_, D_, 1.f, ty, tx);
    else
        gemm128_2ph<1>(sm, xb, D_, Btz, D_, Vt, 0, D_, 1.f, ty, tx);
}

__global__ __launch_bounds__(512) void scores_kernel(
    const ushort* __restrict__ Qb, const ushort* __restrict__ Kb,
    float* __restrict__ Sc, float scale) {
    extern __shared__ ushort sm[];
    const int nwg = gridDim.x;                       // 256 or 64, %8==0
    const int b0 = blockIdx.x;
    const int wg = (b0 & 7) * (nwg >> 3) + (b0 >> 3);
    const int tx = wg & 7, ty = (wg >> 3) & 7, z = wg >> 6;
    gemm256<2>(sm, Qb + (size_t)z * S_ * U_, U_, Kb + (size_t)z * S_ * U_, U_,
               Sc + (size_t)z * S_ * S_, S_, U_, scale, ty, tx);
}

__global__ __launch_bounds__(512) void pv_kernel(
    const ushort* __restrict__ P, const ushort* __restrict__ Vt,
    float* __restrict__ out) {
    extern __shared__ ushort sm[];
    const int nwg = 192;                             // 16 ty x 3 tx x 4 z
    const int b0 = blockIdx.x;
    const int wg = (b0 & 7) * (nwg >> 3) + (b0 >> 3);
    const int z = wg / 48, rem = wg % 48;
    const int ty = rem / 3, tx = rem % 3;
    gemm128_2ph<2>(sm, P + (size_t)z * S_ * S_, S_, Vt + (size_t)z * U_ * S_, S_,
                   out + (size_t)z * S_ * U_, U_, S_, 1.f, ty, tx);
}

// ======================= small helper kernels ========================

__global__ void cast_x_kernel(const float4* __restrict__ in,
                              ushort4* __restrict__ out, int n4) {
    int i = blockIdx.x * 256 + threadIdx.x;
    if (i >= n4) return;
    float4 v = in[i];
    ushort4 o;
    o.x = f2bf(v.x); o.y = f2bf(v.y); o.z = f2bf(v.z); o.w = f2bf(v.w);
    out[i] = o;
}

__global__ void transpose_w_kernel(const float* __restrict__ Wq,
                                   const float* __restrict__ Wk,
                                   const float* __restrict__ Wv,
                                   ushort* __restrict__ Wt) {
    const float* W = blockIdx.z == 0 ? Wq : (blockIdx.z == 1 ? Wk : Wv);
    __shared__ float t[32][33];
    int x0 = blockIdx.x * 32, y0 = blockIdx.y * 32;
    int tx = threadIdx.x;
    for (int i = threadIdx.y; i < 32; i += 8)
        t[i][tx] = W[(size_t)(y0 + i) * U_ + (x0 + tx)];
    __syncthreads();
    ushort* Wtz = Wt + (size_t)blockIdx.z * U_ * D_;
    for (int i = threadIdx.y; i < 32; i += 8)
        Wtz[(size_t)(x0 + i) * D_ + (y0 + tx)] = f2bf(t[tx][i]);
}

__global__ __launch_bounds__(256) void softmax_kernel(
    const float* __restrict__ Sc, ushort* __restrict__ P) {
    size_t row = (size_t)blockIdx.y * gridDim.x + blockIdx.x;
    const float4* r4 = (const float4*)(Sc + row * S_);
    int t = threadIdx.x;
    int w = t >> 6, l = t & 63;
    float4 a = r4[t], b = r4[t + 256];
    float mx = fmaxf(fmaxf(fmaxf(a.x, a.y), fmaxf(a.z, a.w)),
                     fmaxf(fmaxf(b.x, b.y), fmaxf(b.z, b.w)));
#pragma unroll
    for (int off = 32; off; off >>= 1) mx = fmaxf(mx, __shfl_xor(mx, off));
    __shared__ float red[8];
    if (l == 0) red[w] = mx;
    __syncthreads();
    mx = fmaxf(fmaxf(red[0], red[1]), fmaxf(red[2], red[3]));
    float e[8];
    e[0] = __expf(a.x - mx); e[1] = __expf(a.y - mx);
    e[2] = __expf(a.z - mx); e[3] = __expf(a.w - mx);
    e[4] = __expf(b.x - mx); e[5] = __expf(b.y - mx);
    e[6] = __expf(b.z - mx); e[7] = __expf(b.w - mx);
    float s = e[0] + e[1] + e[2] + e[3] + e[4] + e[5] + e[6] + e[7];
#pragma unroll
    for (int off = 32; off; off >>= 1) s += __shfl_xor(s, off);
    if (l == 0) red[4 + w] = s;
    __syncthreads();
    float inv = 1.f / (red[4] + red[5] + red[6] + red[7]);
    ushort4* p4 = (ushort4*)(P + row * S_);
    ushort4 o1, o2;
    o1.x = f2bf(e[0] * inv); o1.y = f2bf(e[1] * inv);
    o1.z = f2bf(e[2] * inv); o1.w = f2bf(e[3] * inv);
    o2.x = f2bf(e[4] * inv); o2.y = f2bf(e[5] * inv);
    o2.z = f2bf(e[6] * inv); o2.w = f2bf(e[7] * inv);
    p4[t] = o1; p4[t + 256] = o2;
}

extern "C" void kernel_launch(void* const* d_in, const int* in_sizes, int n_in,
                              void* d_out, int out_size, void* d_ws, size_t ws_size,
                              hipStream_t stream) {
    (void)in_sizes; (void)n_in; (void)out_size;
    const float* x = (const float*)d_in[0];
    const float* Wq = (const float*)d_in[1];
    const float* Wk = (const float*)d_in[2];
    const float* Wv = (const float*)d_in[3];
    float* out = (float*)d_out;

    char* ws = (char*)d_ws;
    size_t off = 0;
    auto alloc = [&](size_t bytes) -> void* {
        void* p = ws + off;
        off += (bytes + 255) & ~(size_t)255;
        return p;
    };
    ushort* xb = (ushort*)alloc((size_t)B_ * S_ * D_ * 2);
    ushort* Wt = (ushort*)alloc((size_t)3 * U_ * D_ * 2);
    ushort* Qb = (ushort*)alloc((size_t)B_ * S_ * U_ * 2);
    ushort* Kb = (ushort*)alloc((size_t)B_ * S_ * U_ * 2);
    ushort* Vt = (ushort*)alloc((size_t)B_ * S_ * U_ * 2);  // [B][U][S]
    ushort* P  = (ushort*)alloc((size_t)B_ * S_ * S_ * 2);
    bool full = (ws_size - off) >= (size_t)B_ * S_ * S_ * 4 + 256;
    float* Sc = (float*)alloc(full ? (size_t)B_ * S_ * S_ * 4 : (size_t)S_ * S_ * 4);

    hipFuncSetAttribute(reinterpret_cast<const void*>(proj_kernel),
                        hipFuncAttributeMaxDynamicSharedMemorySize, 131072);
    hipFuncSetAttribute(reinterpret_cast<const void*>(scores_kernel),
                        hipFuncAttributeMaxDynamicSharedMemorySize, 131072);
    hipFuncSetAttribute(reinterpret_cast<const void*>(pv_kernel),
                        hipFuncAttributeMaxDynamicSharedMemorySize, 131072);

    int n4 = B_ * S_ * D_ / 4;
    cast_x_kernel<<<(n4 + 255) / 256, 256, 0, stream>>>(
        (const float4*)x, (ushort4*)xb, n4);
    transpose_w_kernel<<<dim3(U_ / 32, D_ / 32, 3), dim3(32, 8), 0, stream>>>(
        Wq, Wk, Wv, Wt);
    proj_kernel<<<576, 512, 98304, stream>>>(xb, Wt, Qb, Kb, Vt);

    const float scale = 0.036084391824351615f;  // 1/sqrt(768)
    if (full) {
        scores_kernel<<<256, 512, 131072, stream>>>(Qb, Kb, Sc, scale);
        softmax_kernel<<<dim3(S_, B_), 256, 0, stream>>>(Sc, P);
    } else {
        for (int b = 0; b < B_; ++b) {
            scores_kernel<<<64, 512, 131072, stream>>>(
                Qb + (size_t)b * S_ * U_, Kb + (size_t)b * S_ * U_, Sc, scale);
            softmax_kernel<<<dim3(S_, 1), 256, 0, stream>>>(
                Sc, P + (size_t)b * S_ * S_);
        }
    }
    pv_kernel<<<192, 512, 98304, stream>>>(P, Vt, out);
}